// Round 6
// baseline (279.358 us; speedup 1.0000x reference)
//
#include <hip/hip_runtime.h>

typedef __attribute__((ext_vector_type(8))) short bf16x8;
typedef __attribute__((ext_vector_type(4))) short bf16x4;
typedef __attribute__((ext_vector_type(4))) float f32x4;

__device__ __forceinline__ unsigned short f2bf(float x){
  unsigned u = __float_as_uint(x);
  u = (u + 0x7fffu + ((u >> 16) & 1u)) >> 16;
  return (unsigned short)u;
}

__device__ __forceinline__ bf16x8 cvtpack8(float4 a, float4 b){
  union { bf16x8 v; unsigned short u[8]; } p;
  p.u[0] = f2bf(a.x); p.u[1] = f2bf(a.y); p.u[2] = f2bf(a.z); p.u[3] = f2bf(a.w);
  p.u[4] = f2bf(b.x); p.u[5] = f2bf(b.y); p.u[6] = f2bf(b.z); p.u[7] = f2bf(b.w);
  return p.v;
}

// ---------------- zero init ----------------
__global__ __launch_bounds__(256) void kzero(float* __restrict__ G0, float* __restrict__ n2){
  int b = blockIdx.x;
  if (b < 256) G0[b * 256 + threadIdx.x] = 0.0f;
  else if (threadIdx.x == 0) *n2 = 0.0f;
}

// ---------------- Bjorck (polar factor) small kernels ----------------

__global__ __launch_bounds__(256) void knorm(const float* __restrict__ wt, float* __restrict__ n2){
  int t = blockIdx.x * 256 + threadIdx.x;
  float4 v = reinterpret_cast<const float4*>(wt)[t];
  float s = v.x*v.x + v.y*v.y + v.z*v.z + v.w*v.w;
  #pragma unroll
  for (int o = 32; o > 0; o >>= 1) s += __shfl_down(s, o, 64);
  __shared__ float red[4];
  if ((threadIdx.x & 63) == 0) red[threadIdx.x >> 6] = s;
  __syncthreads();
  if (threadIdx.x == 0) atomicAdd(n2, red[0] + red[1] + red[2] + red[3]);
}

__global__ __launch_bounds__(256) void kinit(const float* __restrict__ wt, const float* __restrict__ n2,
                                             float* __restrict__ W){
  int c = blockIdx.x;
  int r = threadIdx.x;
  float s = rsqrtf(*n2) * (1.0f / 0.3f);
  W[(size_t)r * 256 + c]         = wt[(size_t)c * 512 + r] * s;
  W[(size_t)(r + 256) * 256 + c] = wt[(size_t)c * 512 + r + 256] * s;
}

// G += partial(W^T W): grid (8 j, 8 i, 8 k-parts), 32x32 tile, k-range 64
__global__ __launch_bounds__(256) void kgram2(const float* __restrict__ W, float* __restrict__ G){
  __shared__ __align__(16) float Wi[64][32];
  __shared__ __align__(16) float Wj[64][32];
  const int t = threadIdx.x;
  const int i0 = blockIdx.y * 32, j0 = blockIdx.x * 32, k0 = blockIdx.z * 64;
  const int lr = t >> 3, lc = (t & 7) * 4;
  #pragma unroll
  for (int p = 0; p < 2; ++p){
    int r = lr + p * 32;
    *reinterpret_cast<float4*>(&Wi[r][lc]) =
        *reinterpret_cast<const float4*>(&W[(size_t)(k0 + r) * 256 + i0 + lc]);
    *reinterpret_cast<float4*>(&Wj[r][lc]) =
        *reinterpret_cast<const float4*>(&W[(size_t)(k0 + r) * 256 + j0 + lc]);
  }
  __syncthreads();
  const int tx = t & 31, iy = t >> 5;
  float g0 = 0, g1 = 0, g2 = 0, g3 = 0;
  #pragma unroll 8
  for (int k = 0; k < 64; ++k){
    float wj = Wj[k][tx];
    float4 wi = *reinterpret_cast<const float4*>(&Wi[k][iy * 4]);
    g0 = fmaf(wi.x, wj, g0); g1 = fmaf(wi.y, wj, g1);
    g2 = fmaf(wi.z, wj, g2); g3 = fmaf(wi.w, wj, g3);
  }
  float* gp = &G[(size_t)(i0 + iy * 4) * 256 + j0 + tx];
  atomicAdd(gp,       g0); atomicAdd(gp + 256, g1);
  atomicAdd(gp + 512, g2); atomicAdd(gp + 768, g3);
}

// W <- ca*W + cb*(W G) + cc*(W G) G ; zeroes Gnext; last: emit k-tiled bf16 WT2
__global__ __launch_bounds__(512) void kupdate2(float* __restrict__ W, const float* __restrict__ G,
    float* __restrict__ Gnext, float ca, float cb, float cc, int last,
    unsigned short* __restrict__ WT2){
  __shared__ float wr[2][256], yl[2][256];
  const int t = threadIdx.x;
  const int c = t & 255, row = t >> 8;
  const int r = blockIdx.x * 2 + row;
  wr[row][c] = W[(size_t)r * 256 + c];
  __syncthreads();
  float y = 0;
  #pragma unroll 8
  for (int k = 0; k < 256; ++k)
    y = fmaf(wr[row][k], G[(size_t)k * 256 + c], y);
  yl[row][c] = y;
  __syncthreads();
  float d = 0;
  #pragma unroll 8
  for (int k = 0; k < 256; ++k)
    d = fmaf(yl[row][k], G[(size_t)k * 256 + c], d);
  float nw = ca * wr[row][c] + cb * y + cc * d;
  W[(size_t)r * 256 + c] = nw;
  if (r < 256) Gnext[(size_t)r * 256 + c] = 0.0f;
  if (last) WT2[((size_t)(r >> 3) * 256 + c) * 8 + (r & 7)] = f2bf(nw);
}

// ---------------- wave-streaming GEMM: C[M,256] = A[M,KDIM](f32) * B(bf16 k-tiled) --
// Each wave: 32 rows x 256 cols, fully independent (no LDS, no barriers).
// A-fragment loaded straight from global in MFMA layout (lane row = l&15,
// k = (l>>4)*8+j) -> lanes {l,l+16,l+32,l+48} cover one full 128B line per row.
// Issue order per k-step: B(s) [L2], then A(s+1) [HBM], then MFMA -> the MFMA's
// FIFO vmcnt wait on B never retires the younger A prefetch.
// B layout: element (k, c) at ((k/8)*256 + c)*8 + k%8
// EPI==0: bf16 k-tiled output (KS must be 1)
// EPI==1: fp32 partial per kp -> Cout + kp*8192*256

template<int KDIM, int KS, int EPI>
__global__ __launch_bounds__(256, 2) void kgemmW(const float* __restrict__ A,
    const unsigned short* __restrict__ B, void* __restrict__ Cout){
  const int t = threadIdx.x;
  const int wave = t >> 6, lane = t & 63;
  const int rlo = lane & 15, l16 = lane >> 4;
  const int kp = (KS > 1) ? (int)(blockIdx.x % KS) : 0;
  const int rb = (KS > 1) ? (int)(blockIdx.x / KS) : (int)blockIdx.x;
  constexpr int KLOC = KDIM / KS;
  constexpr int NS = KLOC / 32;          // K-step = 32 (one MFMA K)
  const int kbase = kp * KLOC;

  const int row0 = rb * 128 + wave * 32 + rlo;
  const float* a0 = A + (size_t)row0 * KDIM + kbase + l16 * 8;
  const float* a1 = a0 + (size_t)16 * KDIM;
  const unsigned short* bp = B + ((size_t)((kbase >> 3) + l16) * 256 + rlo) * 8;

  f32x4 acc[2][16];
  #pragma unroll
  for (int mf = 0; mf < 2; ++mf)
    #pragma unroll
    for (int nf = 0; nf < 16; ++nf){
      acc[mf][nf][0] = 0.f; acc[mf][nf][1] = 0.f;
      acc[mf][nf][2] = 0.f; acc[mf][nf][3] = 0.f;
    }

#define LDA(BUF, S) {                                                     \
    BUF[0][0] = *reinterpret_cast<const float4*>(a0 + (size_t)(S) * 32);      \
    BUF[0][1] = *reinterpret_cast<const float4*>(a0 + (size_t)(S) * 32 + 4);  \
    BUF[1][0] = *reinterpret_cast<const float4*>(a1 + (size_t)(S) * 32);      \
    BUF[1][1] = *reinterpret_cast<const float4*>(a1 + (size_t)(S) * 32 + 4); }
#define LDB(BF, S) {                                                      \
    _Pragma("unroll")                                                     \
    for (int nf = 0; nf < 16; ++nf)                                       \
      BF[nf] = *reinterpret_cast<const bf16x8*>(                          \
          bp + ((size_t)(S) * 4 * 256 + nf * 16) * 8); }
#define FMAS(BUF, BF) {                                                   \
    bf16x8 fr0 = cvtpack8(BUF[0][0], BUF[0][1]);                          \
    bf16x8 fr1 = cvtpack8(BUF[1][0], BUF[1][1]);                          \
    _Pragma("unroll")                                                     \
    for (int nf = 0; nf < 16; ++nf){                                      \
      acc[0][nf] = __builtin_amdgcn_mfma_f32_16x16x32_bf16(fr0, BF[nf], acc[0][nf], 0, 0, 0); \
      acc[1][nf] = __builtin_amdgcn_mfma_f32_16x16x32_bf16(fr1, BF[nf], acc[1][nf], 0, 0, 0); \
    } }

  float4 bufA[2][2], bufB[2][2];
  LDA(bufA, 0);
  for (int s = 0; s < NS; s += 2){        // NS is even (16 or 32)
    bf16x8 bfrA[16];
    LDB(bfrA, s);
    LDA(bufB, s + 1);
    FMAS(bufA, bfrA);
    bf16x8 bfrB[16];
    LDB(bfrB, s + 1);
    if (s + 2 < NS) LDA(bufA, s + 2);
    FMAS(bufB, bfrB);
  }
#undef LDA
#undef LDB
#undef FMAS

  if constexpr (EPI == 0){
    unsigned short* H = reinterpret_cast<unsigned short*>(Cout);
    #pragma unroll
    for (int mf = 0; mf < 2; ++mf)
      #pragma unroll
      for (int nf = 0; nf < 16; ++nf){
        int c  = nf * 16 + rlo;
        int m0 = rb * 128 + wave * 32 + mf * 16 + (l16 << 2);
        union { bf16x4 v; unsigned short u[4]; } p;
        p.u[0] = f2bf(acc[mf][nf][0]);
        p.u[1] = f2bf(acc[mf][nf][1]);
        p.u[2] = f2bf(acc[mf][nf][2]);
        p.u[3] = f2bf(acc[mf][nf][3]);
        size_t off = ((size_t)(m0 >> 3) * 256 + c) * 8 + (m0 & 7);
        *reinterpret_cast<bf16x4*>(&H[off]) = p.v;
      }
  } else {
    float* O = reinterpret_cast<float*>(Cout) + (size_t)kp * 8192 * 256;
    #pragma unroll
    for (int mf = 0; mf < 2; ++mf)
      #pragma unroll
      for (int nf = 0; nf < 16; ++nf){
        int c  = nf * 16 + rlo;
        int m0 = rb * 128 + wave * 32 + mf * 16 + (l16 << 2);
        #pragma unroll
        for (int j = 0; j < 4; ++j)
          O[(size_t)(m0 + j) * 256 + c] = acc[mf][nf][j];
      }
  }
}

// out = relu(sum of 8 partials), float4-vectorized
__global__ __launch_bounds__(256) void kreduce8(const float* __restrict__ P, float* __restrict__ O){
  size_t i = (size_t)blockIdx.x * 256 + threadIdx.x;
  const float4* p = reinterpret_cast<const float4*>(P);
  float4 r = p[i];
  #pragma unroll
  for (int q = 1; q < 8; ++q){
    float4 b = p[i + (size_t)q * 524288];
    r.x += b.x; r.y += b.y; r.z += b.z; r.w += b.w;
  }
  r.x = fmaxf(r.x, 0.f); r.y = fmaxf(r.y, 0.f);
  r.z = fmaxf(r.z, 0.f); r.w = fmaxf(r.w, 0.f);
  reinterpret_cast<float4*>(O)[i] = r;
}

// ---------------- launcher ----------------

extern "C" void kernel_launch(void* const* d_in, const int* in_sizes, int n_in,
                              void* d_out, int out_size, void* d_ws, size_t ws_size,
                              hipStream_t stream) {
  const float* x   = (const float*)d_in[0];   // [8192,512]
  const float* adj = (const float*)d_in[1];   // [8192,8192]
  const float* wt  = (const float*)d_in[2];   // [256,512]
  float* out = (float*)d_out;                 // [8192,256]

  char* ws = (char*)d_ws;
  float* n2            = (float*)ws;                                    // 4 B
  float* W             = (float*)(ws + 4096);                           // 512 KB
  float* G0            = (float*)(ws + 4096 + 524288);                  // 256 KB
  float* G1            = (float*)(ws + 4096 + 524288 + 262144);         // 256 KB
  unsigned short* WT2  = (unsigned short*)(ws + 4096 + 524288 + 2*262144);   // 256 KB
  unsigned short* HT2  = (unsigned short*)(ws + 4096 + 524288 + 3*262144);   // 4 MB
  float* Cpart         = (float*)(ws + 4096 + 524288 + 3*262144 + 4194304);  // 64 MB

  kzero<<<257, 256, 0, stream>>>(G0, n2);
  knorm<<<128, 256, 0, stream>>>(wt, n2);
  kinit<<<256, 256, 0, stream>>>(wt, n2, W);

  // 4 iterations: aggressive quintic, Muon quintic, 2 exact Bjorck steps
  const float ca[4] = { 4.2000f, 3.4445f, 1.875f, 1.875f };
  const float cb[4] = {-9.0000f, -4.7750f, -1.25f, -1.25f };
  const float cc[4] = {-6.8000f, 2.0315f, 0.375f, 0.375f };
  float* Gb[2] = {G0, G1};
  for (int it = 0; it < 4; ++it){
    float* Gc = Gb[it & 1];
    float* Gn = Gb[(it + 1) & 1];
    kgram2<<<dim3(8, 8, 8), 256, 0, stream>>>(W, Gc);
    kupdate2<<<256, 512, 0, stream>>>(W, Gc, Gn, ca[it], cb[it], cc[it], it == 3 ? 1 : 0, WT2);
  }

  // h^T (k-tiled bf16) = x @ W   (64 blocks x 4 waves x 32 rows)
  kgemmW<512, 1, 0><<<64, 256, 0, stream>>>(x, WT2, (void*)HT2);
  // partials: Cpart[kp] = adj[:, kslice] @ h[kslice, :]  (64 row-blocks x 8 kp)
  kgemmW<8192, 8, 1><<<512, 256, 0, stream>>>(adj, HT2, (void*)Cpart);
  // out = relu(sum partials)
  kreduce8<<<2048, 256, 0, stream>>>(Cpart, out);
}

// Round 8
// 230.223 us; speedup vs baseline: 1.2134x; 1.2134x over previous
//
#include <hip/hip_runtime.h>

typedef __attribute__((ext_vector_type(8))) short bf16x8;
typedef __attribute__((ext_vector_type(4))) short bf16x4;
typedef __attribute__((ext_vector_type(4))) float f32x4;

__device__ __forceinline__ unsigned short f2bf(float x){
  unsigned u = __float_as_uint(x);
  u = (u + 0x7fffu + ((u >> 16) & 1u)) >> 16;
  return (unsigned short)u;
}

__device__ __forceinline__ bf16x8 cvtpack8(float4 a, float4 b){
  union { bf16x8 v; unsigned short u[8]; } p;
  p.u[0] = f2bf(a.x); p.u[1] = f2bf(a.y); p.u[2] = f2bf(a.z); p.u[3] = f2bf(a.w);
  p.u[4] = f2bf(b.x); p.u[5] = f2bf(b.y); p.u[6] = f2bf(b.z); p.u[7] = f2bf(b.w);
  return p.v;
}

// async global->LDS, 16B/lane: LDS dest = wave-uniform base + lane*16
__device__ __forceinline__ void gload16(const void* g, void* l){
  __builtin_amdgcn_global_load_lds(
      (const __attribute__((address_space(1))) unsigned int*)g,
      (__attribute__((address_space(3))) unsigned int*)l, 16, 0, 0);
}

// counted sync: retire all but the 16 newest VMEM ops (2 stage-clusters stay in
// flight); drain LDS queue; barrier. Never vmcnt(0) in the main loop.
#define SYNC16() do { \
  asm volatile("s_waitcnt vmcnt(16) lgkmcnt(0)" ::: "memory"); \
  __builtin_amdgcn_s_barrier(); \
  asm volatile("" ::: "memory"); } while(0)

// ---- B tile format (bf16): tile sg covers k in [sg*32, sg*32+32), 16KB:
//   elem = sg*8192 + ((k>>3)&3)*2048 + c*8 + (k&7)      (c in [0,256))
// Contiguous per tile -> verbatim global_load_lds; ds_read_b128 per (c, kchunk)
// is 8-slot spread (2-way, free).

// ---------------- zero init ----------------
__global__ __launch_bounds__(256) void kzero(float* __restrict__ G0, float* __restrict__ n2){
  int b = blockIdx.x;
  if (b < 256) G0[b * 256 + threadIdx.x] = 0.0f;
  else if (threadIdx.x == 0) *n2 = 0.0f;
}

// ---------------- Bjorck (polar factor) small kernels ----------------

__global__ __launch_bounds__(256) void knorm(const float* __restrict__ wt, float* __restrict__ n2){
  int t = blockIdx.x * 256 + threadIdx.x;
  float4 v = reinterpret_cast<const float4*>(wt)[t];
  float s = v.x*v.x + v.y*v.y + v.z*v.z + v.w*v.w;
  #pragma unroll
  for (int o = 32; o > 0; o >>= 1) s += __shfl_down(s, o, 64);
  __shared__ float red[4];
  if ((threadIdx.x & 63) == 0) red[threadIdx.x >> 6] = s;
  __syncthreads();
  if (threadIdx.x == 0) atomicAdd(n2, red[0] + red[1] + red[2] + red[3]);
}

__global__ __launch_bounds__(256) void kinit(const float* __restrict__ wt, const float* __restrict__ n2,
                                             float* __restrict__ W){
  int c = blockIdx.x;
  int r = threadIdx.x;
  float s = rsqrtf(*n2) * (1.0f / 0.3f);
  W[(size_t)r * 256 + c]         = wt[(size_t)c * 512 + r] * s;
  W[(size_t)(r + 256) * 256 + c] = wt[(size_t)c * 512 + r + 256] * s;
}

// G += partial(W^T W): grid (8 j, 8 i, 8 k-parts), 32x32 tile, k-range 64
__global__ __launch_bounds__(256) void kgram2(const float* __restrict__ W, float* __restrict__ G){
  __shared__ __align__(16) float Wi[64][32];
  __shared__ __align__(16) float Wj[64][32];
  const int t = threadIdx.x;
  const int i0 = blockIdx.y * 32, j0 = blockIdx.x * 32, k0 = blockIdx.z * 64;
  const int lr = t >> 3, lc = (t & 7) * 4;
  #pragma unroll
  for (int p = 0; p < 2; ++p){
    int r = lr + p * 32;
    *reinterpret_cast<float4*>(&Wi[r][lc]) =
        *reinterpret_cast<const float4*>(&W[(size_t)(k0 + r) * 256 + i0 + lc]);
    *reinterpret_cast<float4*>(&Wj[r][lc]) =
        *reinterpret_cast<const float4*>(&W[(size_t)(k0 + r) * 256 + j0 + lc]);
  }
  __syncthreads();
  const int tx = t & 31, iy = t >> 5;
  float g0 = 0, g1 = 0, g2 = 0, g3 = 0;
  #pragma unroll 8
  for (int k = 0; k < 64; ++k){
    float wj = Wj[k][tx];
    float4 wi = *reinterpret_cast<const float4*>(&Wi[k][iy * 4]);
    g0 = fmaf(wi.x, wj, g0); g1 = fmaf(wi.y, wj, g1);
    g2 = fmaf(wi.z, wj, g2); g3 = fmaf(wi.w, wj, g3);
  }
  float* gp = &G[(size_t)(i0 + iy * 4) * 256 + j0 + tx];
  atomicAdd(gp,       g0); atomicAdd(gp + 256, g1);
  atomicAdd(gp + 512, g2); atomicAdd(gp + 768, g3);
}

// W <- ca*W + cb*(W G) + cc*(W G) G ; zeroes Gnext; last: emit WT2 in B tile format
__global__ __launch_bounds__(512) void kupdate2(float* __restrict__ W, const float* __restrict__ G,
    float* __restrict__ Gnext, float ca, float cb, float cc, int last,
    unsigned short* __restrict__ WT2){
  __shared__ float wr[2][256], yl[2][256];
  const int t = threadIdx.x;
  const int c = t & 255, row = t >> 8;
  const int r = blockIdx.x * 2 + row;
  wr[row][c] = W[(size_t)r * 256 + c];
  __syncthreads();
  float y = 0;
  #pragma unroll 8
  for (int k = 0; k < 256; ++k)
    y = fmaf(wr[row][k], G[(size_t)k * 256 + c], y);
  yl[row][c] = y;
  __syncthreads();
  float d = 0;
  #pragma unroll 8
  for (int k = 0; k < 256; ++k)
    d = fmaf(yl[row][k], G[(size_t)k * 256 + c], d);
  float nw = ca * wr[row][c] + cb * y + cc * d;
  W[(size_t)r * 256 + c] = nw;
  if (r < 256) Gnext[(size_t)r * 256 + c] = 0.0f;
  if (last){
    size_t e = (size_t)(r >> 5) * 8192 + (size_t)((r >> 3) & 3) * 2048 + (size_t)c * 8 + (r & 7);
    WT2[e] = f2bf(nw);
  }
}

// ------------- all-DMA pipelined GEMM: C[M,256] = A[M,KDIM](f32) * B(bf16 tiles) ----
// BM=128 (4 waves x 32 rows), BK=32, quad-buffered A+B in LDS (128 KB), depth-3
// lookahead, one 8-op global_load_lds cluster per step, SYNC16 per step.
// A LDS: fp32 [128][32] with 16B-slot XOR swizzle (slot ^= row&7), source
// pre-swizzled so DMA dest stays linear. B LDS: tile format (no swizzle needed).
// EPI==0: bf16 output in B tile format (KS must be 1)
// EPI==1: fp32 partial per kp -> Cout + kp*8192*256

template<int KDIM, int KS, int EPI>
__global__ __launch_bounds__(256, 1) void kgemmP(const float* __restrict__ A,
    const unsigned short* __restrict__ B, void* __restrict__ Cout){
  __shared__ __align__(16) float          As[4][4096];   // 4 x 16KB
  __shared__ __align__(16) unsigned short Bs[4][8192];   // 4 x 16KB

  const int t = threadIdx.x;
  const int w = t >> 6, lane = t & 63;
  const int rlo = lane & 15, l16 = lane >> 4;
  const int kp = (KS > 1) ? (int)(blockIdx.x % KS) : 0;  // one kp per XCD (bid%4)
  const int rb = (KS > 1) ? (int)(blockIdx.x / KS) : (int)blockIdx.x;
  constexpr int KLOC = KDIM / KS;
  constexpr int NS = KLOC / 32;          // multiple of 4
  const int kbase = kp * KLOC;

  // A staging: op i covers rows w*32+8i..+7; lane ld covers row +ld/8, stored
  // slot ld&7, content = global k-slot (ld&7)^(ld>>3)  [inverse swizzle at src]
  const int arow = w * 32 + (lane >> 3);
  const float* astage = A + (size_t)(rb * 128 + arow) * KDIM + kbase
                          + (size_t)(((lane & 7) ^ (lane >> 3)) * 4);
  // B staging: verbatim tile copy, wave w covers elements [w*2048, +2048)
  const unsigned short* bstage = B + (size_t)(kbase >> 5) * 8192 + w * 2048 + lane * 8;

  f32x4 acc[2][16];
  #pragma unroll
  for (int mf = 0; mf < 2; ++mf)
    #pragma unroll
    for (int nf = 0; nf < 16; ++nf){
      acc[mf][nf][0] = 0.f; acc[mf][nf][1] = 0.f;
      acc[mf][nf][2] = 0.f; acc[mf][nf][3] = 0.f;
    }

#define STAGE(bi, st) { \
    _Pragma("unroll") \
    for (int i = 0; i < 4; ++i) \
      gload16(astage + (size_t)(st) * 32 + (size_t)i * 8 * KDIM, \
              &As[bi][(w * 32 + i * 8) * 32]); \
    _Pragma("unroll") \
    for (int i = 0; i < 4; ++i) \
      gload16(bstage + (size_t)(st) * 8192 + i * 512, \
              &Bs[bi][w * 2048 + i * 512]); }

#define STEP(p, s) { \
    bf16x8 afr[2]; \
    _Pragma("unroll") \
    for (int mf = 0; mf < 2; ++mf){ \
      int row = w * 32 + mf * 16 + rlo; \
      int s0 = (l16 * 2) ^ (rlo & 7); \
      int s1 = (l16 * 2 + 1) ^ (rlo & 7); \
      float4 f0 = *reinterpret_cast<const float4*>(&As[p][row * 32 + s0 * 4]); \
      float4 f1 = *reinterpret_cast<const float4*>(&As[p][row * 32 + s1 * 4]); \
      afr[mf] = cvtpack8(f0, f1); \
    } \
    bf16x8 bfr[16]; \
    _Pragma("unroll") \
    for (int nf = 0; nf < 16; ++nf) \
      bfr[nf] = *reinterpret_cast<const bf16x8*>(&Bs[p][l16 * 2048 + (nf * 16 + rlo) * 8]); \
    { int st = ((s) + 3 < NS) ? (s) + 3 : NS - 1; STAGE(((p) + 3) & 3, st); } \
    _Pragma("unroll") \
    for (int nf = 0; nf < 16; ++nf){ \
      acc[0][nf] = __builtin_amdgcn_mfma_f32_16x16x32_bf16(afr[0], bfr[nf], acc[0][nf], 0, 0, 0); \
      acc[1][nf] = __builtin_amdgcn_mfma_f32_16x16x32_bf16(afr[1], bfr[nf], acc[1][nf], 0, 0, 0); \
    } \
    SYNC16(); }

  // prologue: 3 clusters in flight, wait for the first
  STAGE(0, 0);
  STAGE(1, 1);
  STAGE(2, 2);
  asm volatile("s_waitcnt vmcnt(16)" ::: "memory");
  __builtin_amdgcn_s_barrier();
  asm volatile("" ::: "memory");

  #pragma unroll 1
  for (int s4 = 0; s4 < NS; s4 += 4){
    STEP(0, s4);
    STEP(1, s4 + 1);
    STEP(2, s4 + 2);
    STEP(3, s4 + 3);
  }
#undef STAGE
#undef STEP

  if constexpr (EPI == 0){
    unsigned short* H = reinterpret_cast<unsigned short*>(Cout);
    #pragma unroll
    for (int mf = 0; mf < 2; ++mf)
      #pragma unroll
      for (int nf = 0; nf < 16; ++nf){
        int c  = nf * 16 + rlo;
        int m0 = rb * 128 + w * 32 + mf * 16 + (l16 << 2);
        size_t e = (size_t)(m0 >> 5) * 8192 + (size_t)((m0 >> 3) & 3) * 2048
                 + (size_t)c * 8 + (m0 & 7);
        union { bf16x4 v; unsigned short u[4]; } p;
        p.u[0] = f2bf(acc[mf][nf][0]);
        p.u[1] = f2bf(acc[mf][nf][1]);
        p.u[2] = f2bf(acc[mf][nf][2]);
        p.u[3] = f2bf(acc[mf][nf][3]);
        *reinterpret_cast<bf16x4*>(&H[e]) = p.v;
      }
  } else {
    float* O = reinterpret_cast<float*>(Cout) + (size_t)kp * 8192 * 256;
    #pragma unroll
    for (int mf = 0; mf < 2; ++mf)
      #pragma unroll
      for (int nf = 0; nf < 16; ++nf){
        int c  = nf * 16 + rlo;
        int m0 = rb * 128 + w * 32 + mf * 16 + (l16 << 2);
        #pragma unroll
        for (int j = 0; j < 4; ++j)
          O[(size_t)(m0 + j) * 256 + c] = acc[mf][nf][j];
      }
  }
}

// out = relu(sum of 4 partials), float4-vectorized
__global__ __launch_bounds__(256) void kreduce4(const float* __restrict__ P, float* __restrict__ O){
  size_t i = (size_t)blockIdx.x * 256 + threadIdx.x;
  const float4* p = reinterpret_cast<const float4*>(P);
  float4 r = p[i];
  #pragma unroll
  for (int q = 1; q < 4; ++q){
    float4 b = p[i + (size_t)q * 524288];
    r.x += b.x; r.y += b.y; r.z += b.z; r.w += b.w;
  }
  r.x = fmaxf(r.x, 0.f); r.y = fmaxf(r.y, 0.f);
  r.z = fmaxf(r.z, 0.f); r.w = fmaxf(r.w, 0.f);
  reinterpret_cast<float4*>(O)[i] = r;
}

// ---------------- launcher ----------------

extern "C" void kernel_launch(void* const* d_in, const int* in_sizes, int n_in,
                              void* d_out, int out_size, void* d_ws, size_t ws_size,
                              hipStream_t stream) {
  const float* x   = (const float*)d_in[0];   // [8192,512]
  const float* adj = (const float*)d_in[1];   // [8192,8192]
  const float* wt  = (const float*)d_in[2];   // [256,512]
  float* out = (float*)d_out;                 // [8192,256]

  char* ws = (char*)d_ws;
  float* n2            = (float*)ws;                                    // 4 B
  float* W             = (float*)(ws + 4096);                           // 512 KB
  float* G0            = (float*)(ws + 4096 + 524288);                  // 256 KB
  float* G1            = (float*)(ws + 4096 + 524288 + 262144);         // 256 KB
  unsigned short* WT2  = (unsigned short*)(ws + 4096 + 524288 + 2*262144);   // 256 KB
  unsigned short* HT2  = (unsigned short*)(ws + 4096 + 524288 + 3*262144);   // 4 MB
  float* Cpart         = (float*)(ws + 4096 + 524288 + 3*262144 + 4194304);  // 32 MB

  kzero<<<257, 256, 0, stream>>>(G0, n2);
  knorm<<<128, 256, 0, stream>>>(wt, n2);
  kinit<<<256, 256, 0, stream>>>(wt, n2, W);

  // 4 iterations: aggressive quintic, Muon quintic, 2 exact Bjorck steps
  const float ca[4] = { 4.2000f, 3.4445f, 1.875f, 1.875f };
  const float cb[4] = {-9.0000f, -4.7750f, -1.25f, -1.25f };
  const float cc[4] = {-6.8000f, 2.0315f, 0.375f, 0.375f };
  float* Gb[2] = {G0, G1};
  for (int it = 0; it < 4; ++it){
    float* Gc = Gb[it & 1];
    float* Gn = Gb[(it + 1) & 1];
    kgram2<<<dim3(8, 8, 8), 256, 0, stream>>>(W, Gc);
    kupdate2<<<256, 512, 0, stream>>>(W, Gc, Gn, ca[it], cb[it], cc[it], it == 3 ? 1 : 0, WT2);
  }

  // h (B tile format, bf16) = x @ W    (64 blocks of BM=128)
  kgemmP<512, 1, 0><<<64, 256, 0, stream>>>(x, WT2, (void*)HT2);
  // partials: Cpart[kp] = adj[:, kslice] @ h[kslice, :]  (64 row-blocks x 4 kp)
  kgemmP<8192, 4, 1><<<256, 256, 0, stream>>>(adj, HT2, (void*)Cpart);
  // out = relu(sum partials)
  kreduce4<<<2048, 256, 0, stream>>>(Cpart, out);
}